// Round 5
// baseline (428.375 us; speedup 1.0000x reference)
//
#include <hip/hip_runtime.h>

#define NN 50000
#define NE 250000
#define NSCAN_BLKS ((NN + 255)/256)
#define EDGE_BLKS ((4*NE + 255)/256)

typedef __attribute__((ext_vector_type(8))) short bf16x8;
typedef __attribute__((ext_vector_type(4))) float f32x4;

__device__ inline ushort f2bf(float f) {          // RNE float->bf16
  uint u = __float_as_uint(f);
  return (ushort)((u + 0x7fffu + ((u >> 16) & 1u)) >> 16);
}
__device__ inline float bf2f(ushort b) { return __uint_as_float(((uint)b) << 16); }

// ---------------- small utils ----------------
__global__ __launch_bounds__(256) void zero_ints(int* __restrict__ p, int n) {
  int i = blockIdx.x*256 + threadIdx.x;
  if (i < n) p[i] = 0;
}
__global__ __launch_bounds__(256) void zero_floats(float* __restrict__ p, int n) {
  int i = blockIdx.x*256 + threadIdx.x;
  if (i < n) p[i] = 0.f;
}

// ---------------- unified CSR build (dst-keyed, etype-ordered sub-rows) ----------------
__global__ __launch_bounds__(256) void count_kernel(const int* __restrict__ edges, int* __restrict__ counts) {
  int idx = blockIdx.x*256 + threadIdx.x;
  if (idx >= 4*NE) return;
  int t = idx / NE, e = idx - t*NE;
  int dst = edges[(size_t)t*2*NE + NE + e];
  atomicAdd(&counts[t*NN + dst], 1);
}

__global__ __launch_bounds__(256) void sumdeg_kernel(const int* __restrict__ counts, int* __restrict__ totdeg) {
  int v = blockIdx.x*256 + threadIdx.x;
  if (v < NN) totdeg[v] = counts[v] + counts[NN+v] + counts[2*NN+v] + counts[3*NN+v];
}

__global__ __launch_bounds__(256) void scan1_kernel(const int* __restrict__ in, int* __restrict__ out, int* __restrict__ bsum, int n) {
  __shared__ int sd[256];
  int i = blockIdx.x*256 + threadIdx.x;
  int v = (i < n) ? in[i] : 0;
  sd[threadIdx.x] = v;
  __syncthreads();
  for (int off = 1; off < 256; off <<= 1) {
    int add = (threadIdx.x >= off) ? sd[threadIdx.x - off] : 0;
    __syncthreads();
    sd[threadIdx.x] += add;
    __syncthreads();
  }
  if (i < n) out[i] = sd[threadIdx.x] - v;          // exclusive within block
  if (threadIdx.x == 255) bsum[blockIdx.x] = sd[255];
}

__global__ __launch_bounds__(1024) void scan2_kernel(int* __restrict__ bsum, int nb) {
  __shared__ int sd[1024];
  int i = threadIdx.x;
  int v = (i < nb) ? bsum[i] : 0;
  sd[i] = v;
  __syncthreads();
  for (int off = 1; off < 1024; off <<= 1) {
    int add = (i >= off) ? sd[i - off] : 0;
    __syncthreads();
    sd[i] += add;
    __syncthreads();
  }
  if (i < nb) bsum[i] = sd[i] - v;
}

__global__ __launch_bounds__(256) void scan3b_kernel(int* __restrict__ rp, const int* __restrict__ bsum, int n, int total) {
  int i = blockIdx.x*256 + threadIdx.x;
  if (i < n) rp[i] += bsum[blockIdx.x];
  if (i == 0) rp[n] = total;
}

__global__ __launch_bounds__(256) void make_cursor_kernel(const int* __restrict__ rp2, const int* __restrict__ counts,
                                                          int* __restrict__ cursor, int* __restrict__ sub_ptr) {
  int v = blockIdx.x*256 + threadIdx.x;
  if (v >= NN) return;
  int b = rp2[v];
  int s1 = b  + counts[v];
  int s2 = s1 + counts[NN+v];
  int s3 = s2 + counts[2*NN+v];
  cursor[v] = b; cursor[NN+v] = s1; cursor[2*NN+v] = s2; cursor[3*NN+v] = s3;
  sub_ptr[NN+v] = s1; sub_ptr[2*NN+v] = s2; sub_ptr[3*NN+v] = s3;
}

__global__ __launch_bounds__(256) void scatter2_kernel(const int* __restrict__ edges, int* __restrict__ cursor,
                                                       int* __restrict__ col2, int* __restrict__ posmap) {
  int idx = blockIdx.x*256 + threadIdx.x;
  if (idx >= 4*NE) return;
  int t = idx / NE, e = idx - t*NE;
  int src = edges[(size_t)t*2*NE + e];
  int dst = edges[(size_t)t*2*NE + NE + e];
  int pos = atomicAdd(&cursor[t*NN + dst], 1);
  col2[pos] = t*NN + src;                            // feat row index
  posmap[idx] = pos;
}

// ---------------- input converts ----------------
__global__ __launch_bounds__(256) void convert_x_kernel(const float* __restrict__ x, ushort* __restrict__ xpad) {
  int i = blockIdx.x*256 + threadIdx.x;     // over NN*64
  if (i >= NN*64) return;
  int k = i & 63, n = i >> 6;
  xpad[i] = (k < 23) ? f2bf(x[n*23 + k]) : (ushort)0;
}

// WTg2[t][144][64]: cols 0..127 = W^T (k padded to 64); col 128+m = W @ {al_h0,al_h1,ar_h0,ar_h1}; 132+ zero
__global__ __launch_bounds__(256) void convert_wt2_kernel(const float* __restrict__ W, const float* __restrict__ al,
                                                          const float* __restrict__ ar, ushort* __restrict__ WTg2, int Kin) {
  int i = blockIdx.x*256 + threadIdx.x;     // over 4*144*64
  if (i >= 4*144*64) return;
  int k = i & 63; int c = (i >> 6) % 144; int t = i / (144*64);
  float val = 0.f;
  if (c < 128) {
    val = (k < Kin) ? W[((size_t)t*Kin + k)*128 + c] : 0.f;
  } else if (c < 132 && k < Kin) {
    int m = c - 128, h = m & 1;
    const float* A = ((m < 2) ? al : ar) + t*128 + h*64;
    const float* wrow = W + ((size_t)t*Kin + k)*128 + h*64;
    float s = 0.f;
    for (int c2 = 0; c2 < 64; ++c2) s += wrow[c2]*A[c2];
    val = s;
  }
  WTg2[((size_t)t*144 + c)*64 + k] = f2bf(val);
}

// ---------------- MFMA GEMM: featu(packed bf16 pair) = h @ W; el/er as extra cols ----------------
// Block 256 = 4 waves; wave = 16 nodes x 144 cols; K=64 via 2x mfma_16x16x32_bf16 per n-block.
// feat stored head-interleaved: dword d (0..63) of a node = (bf16 h0[d], bf16 h1[d]).
__global__ __launch_bounds__(256)
void gemm_mfma_kernel(const ushort* __restrict__ hbf,   // [>=NN+64][64] bf16
                      const ushort* __restrict__ WTg2,  // [4][144][64] bf16
                      uint* __restrict__ featu,         // [4*NN][64] packed
                      float* __restrict__ elr)          // [16][NN]: (m*4+t)*NN+node
{
  __shared__ ushort WT[144*64];
  const int t = blockIdx.y;
  const int tid = threadIdx.x;
  const int wv = tid >> 6, lane = tid & 63;
  const int node0 = blockIdx.x*64;

  {                                           // stage swizzled: 1152 x 16B chunks
    const ushort* src = WTg2 + (size_t)t*144*64;
    for (int i = tid; i < 1152; i += 256) {
      int c = i >> 3, jj = i & 7;
      bf16x8 val = *(const bf16x8*)(src + (size_t)c*64 + jj*8);
      *(bf16x8*)((char*)WT + c*128 + ((jj ^ (c & 7))*16)) = val;
    }
  }
  __syncthreads();

  const int mrow = lane & 15;
  const int kq = lane >> 4;
  const int anode = node0 + wv*16 + mrow;

  const bf16x8 a0 = *(const bf16x8*)(hbf + (size_t)anode*64 + kq*8);
  const bf16x8 a1 = *(const bf16x8*)(hbf + (size_t)anode*64 + 32 + kq*8);

  f32x4 acc[9];
  #pragma unroll
  for (int nb = 0; nb < 9; ++nb) acc[nb] = (f32x4){0.f,0.f,0.f,0.f};

  #pragma unroll
  for (int nb = 0; nb < 9; ++nb) {
    const int c = nb*16 + mrow;
    const bf16x8 b0 = *(const bf16x8*)((const char*)WT + c*128 + ((kq       ^ (c&7))*16));
    const bf16x8 b1 = *(const bf16x8*)((const char*)WT + c*128 + (((4 + kq) ^ (c&7))*16));
    acc[nb] = __builtin_amdgcn_mfma_f32_16x16x32_bf16(a0, b0, acc[nb], 0, 0, 0);
    acc[nb] = __builtin_amdgcn_mfma_f32_16x16x32_bf16(a1, b1, acc[nb], 0, 0, 0);
  }

  const int noder = node0 + wv*16 + kq*4;     // + r
  #pragma unroll
  for (int nb = 0; nb < 4; ++nb) {
    const int d = nb*16 + mrow;               // dim 0..63
    #pragma unroll
    for (int r = 0; r < 4; ++r) {
      if (noder + r < NN) {
        const uint pk = (uint)f2bf(acc[nb][r]) | ((uint)f2bf(acc[nb+4][r]) << 16);
        featu[((size_t)t*NN + noder + r)*64 + d] = pk;
      }
    }
  }
  if (mrow < 4) {                             // el0/el1/er0/er1 from col 128+mrow
    #pragma unroll
    for (int r = 0; r < 4; ++r) {
      if (noder + r < NN)
        elr[(size_t)(mrow*4 + t)*NN + noder + r] = acc[8][r];
    }
  }
}

// ---------------- phase A: per-edge softmax numerators (CSR-position order) ----------------
__global__ __launch_bounds__(256)
void phaseA_kernel(const int* __restrict__ edges, const float* __restrict__ elr,
                   const int* __restrict__ posmap, float* __restrict__ pexp)
{
  int idx = blockIdx.x*256 + threadIdx.x;
  if (idx >= 4*NE) return;
  int t = idx / NE, e = idx - t*NE;
  int src = edges[(size_t)t*2*NE + e];
  int dst = edges[(size_t)t*2*NE + NE + e];
  float u0 = elr[(size_t)(0*4+t)*NN + src] + elr[(size_t)(2*4+t)*NN + dst];
  float u1 = elr[(size_t)(1*4+t)*NN + src] + elr[(size_t)(3*4+t)*NN + dst];
  u0 = (u0 > 0.f) ? u0 : 0.2f*u0;
  u1 = (u1 > 0.f) ? u1 : 0.2f*u1;
  float p0 = __expf(fminf(fmaxf(u0, -60.f), 60.f));
  float p1 = __expf(fminf(fmaxf(u1, -60.f), 60.f));
  int pos = posmap[idx];
  ((float2*)pexp)[pos] = make_float2(p0, p1);
}

// ---------------- gather: wave per node, scalar (s_load) edge metadata, pure FMA stream ----------------
// Lane l owns dims (h0[l], h1[l]) = one dword of the interleaved feat row.
__global__ __launch_bounds__(256)
void gather_kernel(const uint* __restrict__ featu, const float* __restrict__ pexp,
                   const int* __restrict__ col2, const int* __restrict__ row_ptr2,
                   const int* __restrict__ sub_ptr, const float* __restrict__ ball,
                   ushort* __restrict__ hout, int post)
{
  const int v = __builtin_amdgcn_readfirstlane(blockIdx.x*4 + (threadIdx.x >> 6));
  const int lane = threadIdx.x & 63;

  const int b0 = row_ptr2[v];
  const int b4 = row_ptr2[v+1];
  const int s1 = sub_ptr[NN+v], s2 = sub_ptr[2*NN+v], s3 = sub_ptr[3*NN+v];
  const int bounds[5] = {b0, s1, s2, s3, b4};

  float ax = 0.f, ay = 0.f;                    // h0[lane], h1[lane] accumulators

  #pragma unroll
  for (int t = 0; t < 4; ++t) {
    const int lo = bounds[t], hi = bounds[t+1];
    if (lo >= hi) continue;
    float sum0 = 0.f, sum1 = 0.f, tx = 0.f, ty = 0.f;
    #pragma unroll 4
    for (int q = lo; q < hi; ++q) {
      const int c = col2[q];                   // uniform -> s_load
      const float2 p = ((const float2*)pexp)[q];   // uniform -> s_load_dwordx2
      sum0 += p.x; sum1 += p.y;
      const uint w = featu[(uint)c*64u + (uint)lane];
      tx += p.x * __uint_as_float(w << 16);
      ty += p.y * __uint_as_float(w & 0xffff0000u);
    }
    ax += tx * __builtin_amdgcn_rcpf(sum0);
    ay += ty * __builtin_amdgcn_rcpf(sum1);
  }

  // mean over 4 etypes + bias; lane l holds head0/head1 of dim l
  float bx = 0.f, by = 0.f;
  #pragma unroll
  for (int t = 0; t < 4; ++t) { bx += ball[t*128 + lane]; by += ball[t*128 + 64 + lane]; }
  ax = 0.25f*(ax + bx); ay = 0.25f*(ay + by);

  float o;
  if (post) {
    ax = fmaxf(ax, 0.f); ay = fmaxf(ay, 0.f);
    o = 0.5f*(ax + ay) / fmaxf(sqrtf(ax*ax + ay*ay), 1e-12f);
  } else {
    o = 0.5f*(ax + ay);
  }
  hout[(size_t)v*64 + lane] = f2bf(o);
}

// ---------------- final mean over nodes (bf16 input) ----------------
__global__ __launch_bounds__(256) void reduce_nodes(const ushort* __restrict__ hn, float* __restrict__ accum) {
  __shared__ float sd[256];
  int d = threadIdx.x & 63, rg = threadIdx.x >> 6;
  float s = 0.f;
  for (int r = blockIdx.x*4 + rg; r < NN; r += gridDim.x*4) s += bf2f(hn[(size_t)r*64 + d]);
  sd[threadIdx.x] = s;
  __syncthreads();
  if (threadIdx.x < 64) {
    s = sd[threadIdx.x] + sd[threadIdx.x+64] + sd[threadIdx.x+128] + sd[threadIdx.x+192];
    atomicAdd(&accum[threadIdx.x], s);
  }
}
__global__ __launch_bounds__(64) void final_out_kernel(const float* __restrict__ accum, float* __restrict__ out) {
  int d = threadIdx.x;
  if (d < 64) out[d] = accum[d] * (1.0f/NN);
}

// ---------------- launch ----------------
extern "C" void kernel_launch(void* const* d_in, const int* in_sizes, int n_in,
                              void* d_out, int out_size, void* d_ws, size_t ws_size,
                              hipStream_t stream) {
  const float* x     = (const float*)d_in[0];
  const int*   edges = (const int*)d_in[1];
  const float* W[3]  = {(const float*)d_in[2], (const float*)d_in[6], (const float*)d_in[10]};
  const float* al[3] = {(const float*)d_in[3], (const float*)d_in[7], (const float*)d_in[11]};
  const float* ar[3] = {(const float*)d_in[4], (const float*)d_in[8], (const float*)d_in[12]};
  const float* b[3]  = {(const float*)d_in[5], (const float*)d_in[9], (const float*)d_in[13]};

  char* ws = (char*)d_ws;
  auto up = [](size_t x_) { return (x_ + 255) & ~(size_t)255; };

  const size_t szFeat = (size_t)4*NN*64*sizeof(uint);         // 51.2 MB packed
  const size_t szElr  = (size_t)16*NN*sizeof(float);          // 3.2 MB
  const size_t szPex  = (size_t)4*NE*2*sizeof(float);         // 8 MB
  const size_t szPM   = (size_t)4*NE*sizeof(int);             // 4 MB
  const size_t szHB   = (size_t)(NN+64)*64*sizeof(ushort);
  const size_t szWT   = (size_t)4*144*64*sizeof(ushort);
  const size_t szI4   = (size_t)4*NN*sizeof(int);
  const size_t szI1   = (size_t)(NN+1)*sizeof(int);

  size_t o = 0;
  uint*   featu  = (uint*)(ws + o);   o += up(szFeat);
  float*  elr    = (float*)(ws + o);  o += up(szElr);
  float*  pexp   = (float*)(ws + o);  o += up(szPex);
  int*    posmap = (int*)(ws + o);    o += up(szPM);
  int*    col2   = (int*)(ws + o);    o += up(szPM);
  ushort* xpad   = (ushort*)(ws + o); o += up(szHB);
  ushort* hbuf   = (ushort*)(ws + o); o += up(szHB);
  ushort* WTg2   = (ushort*)(ws + o); o += up(szWT);
  float*  accum  = (float*)(ws + o);  o += up(256);
  int* row_ptr2  = (int*)(ws + o);    o += up(szI1);
  int* totdeg    = (int*)(ws + o);    o += up(szI1);
  int* cursor    = (int*)(ws + o);    o += up(szI4);
  int* counts    = (int*)(ws + o);    o += up(szI4);
  int* sub_ptr   = (int*)(ws + o);    o += up(szI4);
  int* bsum      = (int*)(ws + o);    o += up(4096);

  // ---- unified CSR build (once; shared by all layers) ----
  zero_ints<<<(4*NN + 255)/256, 256, 0, stream>>>(counts, 4*NN);
  count_kernel<<<EDGE_BLKS, 256, 0, stream>>>(edges, counts);
  sumdeg_kernel<<<NSCAN_BLKS, 256, 0, stream>>>(counts, totdeg);
  scan1_kernel<<<NSCAN_BLKS, 256, 0, stream>>>(totdeg, row_ptr2, bsum, NN);
  scan2_kernel<<<1, 1024, 0, stream>>>(bsum, NSCAN_BLKS);
  scan3b_kernel<<<NSCAN_BLKS, 256, 0, stream>>>(row_ptr2, bsum, NN, 4*NE);
  make_cursor_kernel<<<NSCAN_BLKS, 256, 0, stream>>>(row_ptr2, counts, cursor, sub_ptr);
  scatter2_kernel<<<EDGE_BLKS, 256, 0, stream>>>(edges, cursor, col2, posmap);

  convert_x_kernel<<<(NN*64 + 255)/256, 256, 0, stream>>>(x, xpad);

  const int gemmGX = (NN + 63)/64;

  for (int l = 0; l < 3; ++l) {
    const ushort* hin = (l == 0) ? xpad : hbuf;
    convert_wt2_kernel<<<(4*144*64 + 255)/256, 256, 0, stream>>>(W[l], al[l], ar[l], WTg2, (l == 0) ? 23 : 64);
    gemm_mfma_kernel<<<dim3(gemmGX, 4), 256, 0, stream>>>(hin, WTg2, featu, elr);
    phaseA_kernel<<<EDGE_BLKS, 256, 0, stream>>>(edges, elr, posmap, pexp);
    gather_kernel<<<NN/4, 256, 0, stream>>>(featu, pexp, col2, row_ptr2, sub_ptr, b[l], hbuf, (l < 2) ? 1 : 0);
  }

  zero_floats<<<1, 64, 0, stream>>>(accum, 64);
  reduce_nodes<<<256, 256, 0, stream>>>(hbuf, accum);
  final_out_kernel<<<1, 64, 0, stream>>>(accum, (float*)d_out);
}

// Round 6
// 409.465 us; speedup vs baseline: 1.0462x; 1.0462x over previous
//
#include <hip/hip_runtime.h>

#define NN 50000
#define NE 250000
#define NSCAN_BLKS ((NN + 255)/256)
#define EDGE_BLKS ((4*NE + 255)/256)

typedef __attribute__((ext_vector_type(8))) short bf16x8;
typedef __attribute__((ext_vector_type(4))) float f32x4;

__device__ inline ushort f2bf(float f) {          // RNE float->bf16
  uint u = __float_as_uint(f);
  return (ushort)((u + 0x7fffu + ((u >> 16) & 1u)) >> 16);
}
__device__ inline float bf2f(ushort b) { return __uint_as_float(((uint)b) << 16); }

// ---------------- small utils ----------------
__global__ __launch_bounds__(256) void zero_ints(int* __restrict__ p, int n) {
  int i = blockIdx.x*256 + threadIdx.x;
  if (i < n) p[i] = 0;
}
__global__ __launch_bounds__(256) void zero_floats(float* __restrict__ p, int n) {
  int i = blockIdx.x*256 + threadIdx.x;
  if (i < n) p[i] = 0.f;
}

// ---------------- unified CSR build (dst-keyed, etype-ordered sub-rows) ----------------
__global__ __launch_bounds__(256) void count_kernel(const int* __restrict__ edges, int* __restrict__ counts) {
  int idx = blockIdx.x*256 + threadIdx.x;
  if (idx >= 4*NE) return;
  int t = idx / NE, e = idx - t*NE;
  int dst = edges[(size_t)t*2*NE + NE + e];
  atomicAdd(&counts[t*NN + dst], 1);
}

__global__ __launch_bounds__(256) void sumdeg_kernel(const int* __restrict__ counts, int* __restrict__ totdeg) {
  int v = blockIdx.x*256 + threadIdx.x;
  if (v < NN) totdeg[v] = counts[v] + counts[NN+v] + counts[2*NN+v] + counts[3*NN+v];
}

__global__ __launch_bounds__(256) void scan1_kernel(const int* __restrict__ in, int* __restrict__ out, int* __restrict__ bsum, int n) {
  __shared__ int sd[256];
  int i = blockIdx.x*256 + threadIdx.x;
  int v = (i < n) ? in[i] : 0;
  sd[threadIdx.x] = v;
  __syncthreads();
  for (int off = 1; off < 256; off <<= 1) {
    int add = (threadIdx.x >= off) ? sd[threadIdx.x - off] : 0;
    __syncthreads();
    sd[threadIdx.x] += add;
    __syncthreads();
  }
  if (i < n) out[i] = sd[threadIdx.x] - v;          // exclusive within block
  if (threadIdx.x == 255) bsum[blockIdx.x] = sd[255];
}

__global__ __launch_bounds__(1024) void scan2_kernel(int* __restrict__ bsum, int nb) {
  __shared__ int sd[1024];
  int i = threadIdx.x;
  int v = (i < nb) ? bsum[i] : 0;
  sd[i] = v;
  __syncthreads();
  for (int off = 1; off < 1024; off <<= 1) {
    int add = (i >= off) ? sd[i - off] : 0;
    __syncthreads();
    sd[i] += add;
    __syncthreads();
  }
  if (i < nb) bsum[i] = sd[i] - v;
}

__global__ __launch_bounds__(256) void scan3b_kernel(int* __restrict__ rp, const int* __restrict__ bsum, int n, int total) {
  int i = blockIdx.x*256 + threadIdx.x;
  if (i < n) rp[i] += bsum[blockIdx.x];
  if (i == 0) rp[n] = total;
}

__global__ __launch_bounds__(256) void make_cursor_kernel(const int* __restrict__ rp2, const int* __restrict__ counts,
                                                          int* __restrict__ cursor, int* __restrict__ sub_ptr) {
  int v = blockIdx.x*256 + threadIdx.x;
  if (v >= NN) return;
  int b = rp2[v];
  int s1 = b  + counts[v];
  int s2 = s1 + counts[NN+v];
  int s3 = s2 + counts[2*NN+v];
  cursor[v] = b; cursor[NN+v] = s1; cursor[2*NN+v] = s2; cursor[3*NN+v] = s3;
  sub_ptr[NN+v] = s1; sub_ptr[2*NN+v] = s2; sub_ptr[3*NN+v] = s3;
}

__global__ __launch_bounds__(256) void scatter2_kernel(const int* __restrict__ edges, int* __restrict__ cursor,
                                                       int* __restrict__ col2) {
  int idx = blockIdx.x*256 + threadIdx.x;
  if (idx >= 4*NE) return;
  int t = idx / NE, e = idx - t*NE;
  int src = edges[(size_t)t*2*NE + e];
  int dst = edges[(size_t)t*2*NE + NE + e];
  int pos = atomicAdd(&cursor[t*NN + dst], 1);
  col2[pos] = t*NN + src;                            // feat/elp row index
}

// ---------------- input converts ----------------
__global__ __launch_bounds__(256) void convert_x_kernel(const float* __restrict__ x, ushort* __restrict__ xpad) {
  int i = blockIdx.x*256 + threadIdx.x;     // over NN*64
  if (i >= NN*64) return;
  int k = i & 63, n = i >> 6;
  xpad[i] = (k < 23) ? f2bf(x[n*23 + k]) : (ushort)0;
}

// WTg2[t][144][64]: cols 0..127 = W^T (k padded to 64); col 128+m = W @ {al_h0,al_h1,ar_h0,ar_h1}; 132+ zero
__global__ __launch_bounds__(256) void convert_wt2_kernel(const float* __restrict__ W, const float* __restrict__ al,
                                                          const float* __restrict__ ar, ushort* __restrict__ WTg2, int Kin) {
  int i = blockIdx.x*256 + threadIdx.x;     // over 4*144*64
  if (i >= 4*144*64) return;
  int k = i & 63; int c = (i >> 6) % 144; int t = i / (144*64);
  float val = 0.f;
  if (c < 128) {
    val = (k < Kin) ? W[((size_t)t*Kin + k)*128 + c] : 0.f;
  } else if (c < 132 && k < Kin) {
    int m = c - 128, h = m & 1;
    const float* A = ((m < 2) ? al : ar) + t*128 + h*64;
    const float* wrow = W + ((size_t)t*Kin + k)*128 + h*64;
    float s = 0.f;
    for (int c2 = 0; c2 < 64; ++c2) s += wrow[c2]*A[c2];
    val = s;
  }
  WTg2[((size_t)t*144 + c)*64 + k] = f2bf(val);
}

// ---------------- MFMA GEMM: featu(packed bf16 pair) = h @ W; el/er as extra cols ----------------
// Block 256 = 4 waves; wave = 16 nodes x 144 cols; K=64 via 2x mfma_16x16x32_bf16 per n-block.
// feat stored head-interleaved: dword d (0..63) of a node = (bf16 h0[d], bf16 h1[d]).
// el/er stored head-packed: elp[(t*NN+node)*2 + h], erp likewise.
__global__ __launch_bounds__(256)
void gemm_mfma_kernel(const ushort* __restrict__ hbf,   // [>=NN+64][64] bf16
                      const ushort* __restrict__ WTg2,  // [4][144][64] bf16
                      uint* __restrict__ featu,         // [4*NN][64] packed
                      float* __restrict__ elp, float* __restrict__ erp)
{
  __shared__ ushort WT[144*64];
  const int t = blockIdx.y;
  const int tid = threadIdx.x;
  const int wv = tid >> 6, lane = tid & 63;
  const int node0 = blockIdx.x*64;

  {                                           // stage swizzled: 1152 x 16B chunks
    const ushort* src = WTg2 + (size_t)t*144*64;
    for (int i = tid; i < 1152; i += 256) {
      int c = i >> 3, jj = i & 7;
      bf16x8 val = *(const bf16x8*)(src + (size_t)c*64 + jj*8);
      *(bf16x8*)((char*)WT + c*128 + ((jj ^ (c & 7))*16)) = val;
    }
  }
  __syncthreads();

  const int mrow = lane & 15;
  const int kq = lane >> 4;
  const int anode = node0 + wv*16 + mrow;

  const bf16x8 a0 = *(const bf16x8*)(hbf + (size_t)anode*64 + kq*8);
  const bf16x8 a1 = *(const bf16x8*)(hbf + (size_t)anode*64 + 32 + kq*8);

  f32x4 acc[9];
  #pragma unroll
  for (int nb = 0; nb < 9; ++nb) acc[nb] = (f32x4){0.f,0.f,0.f,0.f};

  #pragma unroll
  for (int nb = 0; nb < 9; ++nb) {
    const int c = nb*16 + mrow;
    const bf16x8 b0 = *(const bf16x8*)((const char*)WT + c*128 + ((kq       ^ (c&7))*16));
    const bf16x8 b1 = *(const bf16x8*)((const char*)WT + c*128 + (((4 + kq) ^ (c&7))*16));
    acc[nb] = __builtin_amdgcn_mfma_f32_16x16x32_bf16(a0, b0, acc[nb], 0, 0, 0);
    acc[nb] = __builtin_amdgcn_mfma_f32_16x16x32_bf16(a1, b1, acc[nb], 0, 0, 0);
  }

  const int noder = node0 + wv*16 + kq*4;     // + r
  #pragma unroll
  for (int nb = 0; nb < 4; ++nb) {
    const int d = nb*16 + mrow;               // dim 0..63
    #pragma unroll
    for (int r = 0; r < 4; ++r) {
      if (noder + r < NN) {
        const uint pk = (uint)f2bf(acc[nb][r]) | ((uint)f2bf(acc[nb+4][r]) << 16);
        featu[((size_t)t*NN + noder + r)*64 + d] = pk;
      }
    }
  }
  if (mrow < 4) {                             // col 128+mrow: {el_h0, el_h1, er_h0, er_h1}
    const int h = mrow & 1;
    float* dstp = (mrow < 2) ? elp : erp;
    #pragma unroll
    for (int r = 0; r < 4; ++r) {
      if (noder + r < NN)
        dstp[((size_t)t*NN + noder + r)*2 + h] = acc[8][r];
    }
  }
}

// ---------------- gather: wave per node; inline softmax from elp/erp; pure FMA stream ----------------
// Lane l owns dims (h0[l], h1[l]) = one dword of the interleaved feat row.
__global__ __launch_bounds__(256)
void gather_kernel(const uint* __restrict__ featu, const float* __restrict__ elp,
                   const float* __restrict__ erp, const int* __restrict__ col2,
                   const int* __restrict__ row_ptr2, const int* __restrict__ sub_ptr,
                   const float* __restrict__ ball, ushort* __restrict__ hout, int post)
{
  const int v = __builtin_amdgcn_readfirstlane(blockIdx.x*4 + (threadIdx.x >> 6));
  const int lane = threadIdx.x & 63;

  const int b0 = row_ptr2[v];
  const int b4 = row_ptr2[v+1];
  const int s1 = sub_ptr[NN+v], s2 = sub_ptr[2*NN+v], s3 = sub_ptr[3*NN+v];
  const int bounds[5] = {b0, s1, s2, s3, b4};

  float ax = 0.f, ay = 0.f;                    // h0[lane], h1[lane] accumulators

  #pragma unroll
  for (int t = 0; t < 4; ++t) {
    const int lo = bounds[t], hi = bounds[t+1];
    if (lo >= hi) continue;
    const float2 er2 = ((const float2*)erp)[(size_t)t*NN + v];   // uniform per row
    float sum0 = 0.f, sum1 = 0.f, tx = 0.f, ty = 0.f;
    #pragma unroll 4
    for (int q = lo; q < hi; ++q) {
      const int c = col2[q];                       // uniform -> s_load
      const float2 e2 = ((const float2*)elp)[c];   // uniform -> s_load_dwordx2
      float u0 = e2.x + er2.x, u1 = e2.y + er2.y;
      u0 = (u0 > 0.f) ? u0 : 0.2f*u0;
      u1 = (u1 > 0.f) ? u1 : 0.2f*u1;
      const float p0 = __expf(fminf(fmaxf(u0, -60.f), 60.f));
      const float p1 = __expf(fminf(fmaxf(u1, -60.f), 60.f));
      sum0 += p0; sum1 += p1;
      const uint w = featu[(uint)c*64u + (uint)lane];
      tx += p0 * __uint_as_float(w << 16);
      ty += p1 * __uint_as_float(w & 0xffff0000u);
    }
    ax += tx * __builtin_amdgcn_rcpf(sum0);
    ay += ty * __builtin_amdgcn_rcpf(sum1);
  }

  // mean over 4 etypes + bias; lane l holds head0/head1 of dim l
  float bx = 0.f, by = 0.f;
  #pragma unroll
  for (int t = 0; t < 4; ++t) { bx += ball[t*128 + lane]; by += ball[t*128 + 64 + lane]; }
  ax = 0.25f*(ax + bx); ay = 0.25f*(ay + by);

  float o;
  if (post) {
    ax = fmaxf(ax, 0.f); ay = fmaxf(ay, 0.f);
    o = 0.5f*(ax + ay) / fmaxf(sqrtf(ax*ax + ay*ay), 1e-12f);
  } else {
    o = 0.5f*(ax + ay);
  }
  hout[(size_t)v*64 + lane] = f2bf(o);
}

// ---------------- final mean over nodes (bf16 input) ----------------
__global__ __launch_bounds__(256) void reduce_nodes(const ushort* __restrict__ hn, float* __restrict__ accum) {
  __shared__ float sd[256];
  int d = threadIdx.x & 63, rg = threadIdx.x >> 6;
  float s = 0.f;
  for (int r = blockIdx.x*4 + rg; r < NN; r += gridDim.x*4) s += bf2f(hn[(size_t)r*64 + d]);
  sd[threadIdx.x] = s;
  __syncthreads();
  if (threadIdx.x < 64) {
    s = sd[threadIdx.x] + sd[threadIdx.x+64] + sd[threadIdx.x+128] + sd[threadIdx.x+192];
    atomicAdd(&accum[threadIdx.x], s);
  }
}
__global__ __launch_bounds__(64) void final_out_kernel(const float* __restrict__ accum, float* __restrict__ out) {
  int d = threadIdx.x;
  if (d < 64) out[d] = accum[d] * (1.0f/NN);
}

// ---------------- launch ----------------
extern "C" void kernel_launch(void* const* d_in, const int* in_sizes, int n_in,
                              void* d_out, int out_size, void* d_ws, size_t ws_size,
                              hipStream_t stream) {
  const float* x     = (const float*)d_in[0];
  const int*   edges = (const int*)d_in[1];
  const float* W[3]  = {(const float*)d_in[2], (const float*)d_in[6], (const float*)d_in[10]};
  const float* al[3] = {(const float*)d_in[3], (const float*)d_in[7], (const float*)d_in[11]};
  const float* ar[3] = {(const float*)d_in[4], (const float*)d_in[8], (const float*)d_in[12]};
  const float* b[3]  = {(const float*)d_in[5], (const float*)d_in[9], (const float*)d_in[13]};

  char* ws = (char*)d_ws;
  auto up = [](size_t x_) { return (x_ + 255) & ~(size_t)255; };

  const size_t szFeat = (size_t)4*NN*64*sizeof(uint);         // 51.2 MB packed
  const size_t szElp  = (size_t)4*NN*2*sizeof(float);         // 1.6 MB each
  const size_t szCol  = (size_t)4*NE*sizeof(int);             // 4 MB
  const size_t szHB   = (size_t)(NN+64)*64*sizeof(ushort);
  const size_t szWT   = (size_t)4*144*64*sizeof(ushort);
  const size_t szI4   = (size_t)4*NN*sizeof(int);
  const size_t szI1   = (size_t)(NN+1)*sizeof(int);

  size_t o = 0;
  uint*   featu  = (uint*)(ws + o);   o += up(szFeat);
  float*  elp    = (float*)(ws + o);  o += up(szElp);
  float*  erp    = (float*)(ws + o);  o += up(szElp);
  int*    col2   = (int*)(ws + o);    o += up(szCol);
  ushort* xpad   = (ushort*)(ws + o); o += up(szHB);
  ushort* hbuf   = (ushort*)(ws + o); o += up(szHB);
  ushort* WTg2   = (ushort*)(ws + o); o += up(szWT);
  float*  accum  = (float*)(ws + o);  o += up(256);
  int* row_ptr2  = (int*)(ws + o);    o += up(szI1);
  int* totdeg    = (int*)(ws + o);    o += up(szI1);
  int* cursor    = (int*)(ws + o);    o += up(szI4);
  int* counts    = (int*)(ws + o);    o += up(szI4);
  int* sub_ptr   = (int*)(ws + o);    o += up(szI4);
  int* bsum      = (int*)(ws + o);    o += up(4096);

  // ---- unified CSR build (once; shared by all layers) ----
  zero_ints<<<(4*NN + 255)/256, 256, 0, stream>>>(counts, 4*NN);
  count_kernel<<<EDGE_BLKS, 256, 0, stream>>>(edges, counts);
  sumdeg_kernel<<<NSCAN_BLKS, 256, 0, stream>>>(counts, totdeg);
  scan1_kernel<<<NSCAN_BLKS, 256, 0, stream>>>(totdeg, row_ptr2, bsum, NN);
  scan2_kernel<<<1, 1024, 0, stream>>>(bsum, NSCAN_BLKS);
  scan3b_kernel<<<NSCAN_BLKS, 256, 0, stream>>>(row_ptr2, bsum, NN, 4*NE);
  make_cursor_kernel<<<NSCAN_BLKS, 256, 0, stream>>>(row_ptr2, counts, cursor, sub_ptr);
  scatter2_kernel<<<EDGE_BLKS, 256, 0, stream>>>(edges, cursor, col2);

  convert_x_kernel<<<(NN*64 + 255)/256, 256, 0, stream>>>(x, xpad);

  const int gemmGX = (NN + 63)/64;

  for (int l = 0; l < 3; ++l) {
    const ushort* hin = (l == 0) ? xpad : hbuf;
    convert_wt2_kernel<<<(4*144*64 + 255)/256, 256, 0, stream>>>(W[l], al[l], ar[l], WTg2, (l == 0) ? 23 : 64);
    gemm_mfma_kernel<<<dim3(gemmGX, 4), 256, 0, stream>>>(hin, WTg2, featu, elp, erp);
    gather_kernel<<<NN/4, 256, 0, stream>>>(featu, elp, erp, col2, row_ptr2, sub_ptr, b[l], hbuf, (l < 2) ? 1 : 0);
  }

  zero_floats<<<1, 64, 0, stream>>>(accum, 64);
  reduce_nodes<<<256, 256, 0, stream>>>(hbuf, accum);
  final_out_kernel<<<1, 64, 0, stream>>>(accum, (float*)d_out);
}